// Round 4
// baseline (4681.084 us; speedup 1.0000x reference)
//
#include <hip/hip_runtime.h>
#include <math.h>

// forecastRNN on MI355X, round 4.
// - Recurrence: 32 batch-split blocks, W_hh streamed into REGISTERS
//   (coalesced dwordx4, double-buffered, no barriers in K-loop); h in LDS
//   double buffer, 1 barrier/step.
// - Decode: 224 stage-specialized persistent blocks, weight slices resident
//   in LDS (~130 KB/block) for all 16 steps; A-operands register-direct with
//   prefetch depth 4; two-level grid barrier (28 groups x 8).
// - XW + autoenc remain m97-style mfma_gemm launches.

typedef unsigned short ushort_t;
typedef __attribute__((ext_vector_type(8))) short short8;
typedef __attribute__((ext_vector_type(4))) float f32x4;

#define BB 512
#define TT 65
#define TN 64
#define FF 512
#define HD 1000
#define HDP 1024
#define EPSBN 1e-5f
#define BF (BB*FF)          // 262144
#define MALL (BB*TN)        // 32768
#define CH 4
#define CM (MALL/CH)        // 8192
#define HP 520              // LDS h row stride (1040 B = 65*16)
#define DNB 224
#define NGRP 28

__device__ __forceinline__ ushort_t f2bf(float f) {
    union { float f; unsigned u; } v; v.f = f;
    unsigned r = v.u + 0x7FFFu + ((v.u >> 16) & 1u);
    return (ushort_t)(r >> 16);
}

__device__ __forceinline__ void ld16(const ushort_t* g, ushort_t* l) {
    __builtin_amdgcn_global_load_lds(
        (const __attribute__((address_space(1))) unsigned*)g,
        (__attribute__((address_space(3))) unsigned*)l, 16, 0, 0);
}

// ---------------------------------------------------------------------------
// Large-GEMM kernel (XW precompute + autoenc), 128x128 tile, BK=32.
// epi 0: out_f32 = acc + p1 + p2
// epi 2: out_bf16 = BN(acc) (0 for col >= Nreal)
// epi 5: BN(acc): tau<63 -> loss1 partial vs aux(=x); tau==63 -> seed bf16
// ---------------------------------------------------------------------------
__global__ __launch_bounds__(256)
void mfma_gemm(const ushort_t* __restrict__ A, long a_rs,
               const ushort_t* __restrict__ W, int K, int Nreal,
               void* __restrict__ outv, long o_rs,
               const float* __restrict__ aux, int epi, int mbase,
               const float* __restrict__ p1, const float* __restrict__ p2,
               const float* __restrict__ rm, const float* __restrict__ rv,
               const float* __restrict__ gg, const float* __restrict__ be,
               ushort_t* __restrict__ out2, float* __restrict__ sums)
{
    __shared__ ushort_t As[128 * 32];
    __shared__ ushort_t Bs[128 * 32];
    __shared__ float red[256];

    const int tid  = threadIdx.x;
    const int wave = tid >> 6, lane = tid & 63;
    const int wm = wave >> 1, wn = wave & 1;
    const int tileM = blockIdx.y * 128, tileN = blockIdx.x * 128;

    f32x4 acc[4][4] = {};
    const int srow = lane >> 2;
    const int skb  = (lane & 3) * 8;

    for (int kt = 0; kt < K; kt += 32) {
        __syncthreads();
#pragma unroll
        for (int s = 0; s < 2; ++s) {
            const int instr = wave * 2 + s;
            const int row = instr * 16 + srow;
            ld16(A + (size_t)(tileM + row) * a_rs + kt + skb, &As[instr * 512]);
            ld16(W + (size_t)(tileN + row) * (size_t)K + kt + skb, &Bs[instr * 512]);
        }
        __syncthreads();
        const int lr = lane & 15;
        const int lk = (lane >> 4) * 8;
        short8 af[4], bfr[4];
#pragma unroll
        for (int i = 0; i < 4; ++i)
            af[i] = *(const short8*)&As[(wm * 64 + i * 16 + lr) * 32 + lk];
#pragma unroll
        for (int j = 0; j < 4; ++j)
            bfr[j] = *(const short8*)&Bs[(wn * 64 + j * 16 + lr) * 32 + lk];
#pragma unroll
        for (int i = 0; i < 4; ++i)
#pragma unroll
            for (int j = 0; j < 4; ++j)
                acc[i][j] = __builtin_amdgcn_mfma_f32_16x16x32_bf16(
                    af[i], bfr[j], acc[i][j], 0, 0, 0);
    }

    const int lr = lane & 15;
    const int rquad = (lane >> 4) * 4;
    float lsum = 0.f;
#pragma unroll
    for (int i = 0; i < 4; ++i) {
#pragma unroll
        for (int r = 0; r < 4; ++r) {
            const int grow = tileM + wm * 64 + i * 16 + rquad + r;
#pragma unroll
            for (int j = 0; j < 4; ++j) {
                const int gcol = tileN + wn * 64 + j * 16 + lr;
                const float v = acc[i][j][r];
                if (epi == 0) {
                    ((float*)outv)[(size_t)grow * o_rs + gcol] = v + p1[gcol] + p2[gcol];
                } else if (epi == 2) {
                    float o = 0.f;
                    if (gcol < Nreal) {
                        const float s = gg[gcol] * rsqrtf(rv[gcol] + EPSBN);
                        o = (v + p1[gcol] - rm[gcol]) * s + be[gcol];
                    }
                    ((ushort_t*)outv)[(size_t)grow * o_rs + gcol] = f2bf(o);
                } else { // epi 5
                    const float s = gg[gcol] * rsqrtf(rv[gcol] + EPSBN);
                    const float o = (v + p1[gcol] - rm[gcol]) * s + be[gcol];
                    const int gm = mbase + grow;
                    const int b = gm >> 6, tau = gm & 63;
                    if (tau < 63) {
                        const float d = o - aux[((size_t)b * TT + tau + 1) * FF + gcol];
                        lsum += d * d;
                    } else {
                        out2[(size_t)b * FF + gcol] = f2bf(o);
                    }
                }
            }
        }
    }
    if (epi == 5) {
        red[tid] = lsum;
        __syncthreads();
        for (int o = 128; o > 0; o >>= 1) {
            if (tid < o) red[tid] += red[tid + o];
            __syncthreads();
        }
        if (tid == 0) atomicAdd(&sums[0], red[0]);
    }
}

// ---------------------------------------------------------------------------
// Persistent recurrence: 32 blocks x 16 batch rows. W_hh fragments loaded
// straight to registers (coalesced); h double-buffered in LDS; 1 barrier/step.
// ---------------------------------------------------------------------------
__global__ __launch_bounds__(256)
void rnn_persistent(const ushort_t* __restrict__ Whh,
                    const float* __restrict__ XW,
                    ushort_t* __restrict__ hs)
{
    __shared__ ushort_t hb[2][16 * HP];
    const int tid = threadIdx.x, wave = tid >> 6, lane = tid & 63;
    const int b0 = blockIdx.x * 16;
    const int lr = lane & 15, lq = lane >> 4;

    // t = 0: h = tanh(XW_0)
    for (int it = 0; it < 8; ++it) {
        const int e = (it * 256 + tid) * 4;
        const int row = e >> 9, col = e & 511;
        const size_t gi = ((size_t)(b0 + row) * TN) * FF + col;
        const float4 v = *(const float4*)&XW[gi];
        const ushort_t h0 = f2bf(tanhf(v.x)), h1 = f2bf(tanhf(v.y));
        const ushort_t h2 = f2bf(tanhf(v.z)), h3 = f2bf(tanhf(v.w));
        hb[0][row * HP + col + 0] = h0; hb[0][row * HP + col + 1] = h1;
        hb[0][row * HP + col + 2] = h2; hb[0][row * HP + col + 3] = h3;
        unsigned r0 = (unsigned)h0 | ((unsigned)h1 << 16);
        unsigned r1 = (unsigned)h2 | ((unsigned)h3 << 16);
        *(uint2*)&hs[gi] = make_uint2(r0, r1);
    }
    __syncthreads();

    const int c0 = wave * 128;
    for (int t = 1; t < TN; ++t) {
        const ushort_t* hcur = hb[(t - 1) & 1];
        f32x4 acc[8] = {};
        short8 wf[2][8];
        short8 af[2];
        af[0] = *(const short8*)&hcur[lr * HP + lq * 8];
#pragma unroll
        for (int j = 0; j < 8; ++j)
            wf[0][j] = *(const short8*)(Whh + (size_t)(c0 + j * 16 + lr) * FF + lq * 8);
#pragma unroll
        for (int kc = 0; kc < 16; ++kc) {
            const int b = kc & 1, nb = b ^ 1;
            if (kc < 15) {
                const int kk = (kc + 1) * 32 + lq * 8;
                af[nb] = *(const short8*)&hcur[lr * HP + kk];
#pragma unroll
                for (int j = 0; j < 8; ++j)
                    wf[nb][j] = *(const short8*)(Whh + (size_t)(c0 + j * 16 + lr) * FF + kk);
            }
#pragma unroll
            for (int j = 0; j < 8; ++j)
                acc[j] = __builtin_amdgcn_mfma_f32_16x16x32_bf16(
                    af[b], wf[b][j], acc[j], 0, 0, 0);
        }
        ushort_t* hnxt = hb[t & 1];
#pragma unroll
        for (int j = 0; j < 8; ++j) {
            const int col = c0 + j * 16 + lr;
#pragma unroll
            for (int r = 0; r < 4; ++r) {
                const int row = lq * 4 + r;
                const size_t gi = ((size_t)(b0 + row) * TN + t) * FF + col;
                const ushort_t hv = f2bf(tanhf(acc[j][r] + XW[gi]));
                hnxt[row * HP + col] = hv;
                hs[gi] = hv;
            }
        }
        __syncthreads();
    }
}

// ---------------------------------------------------------------------------
// Two-level grid barrier for DNB blocks (28 groups x 8), monotonic counters.
// ---------------------------------------------------------------------------
__device__ __forceinline__ void gbar(unsigned* __restrict__ c1,
                                     unsigned* __restrict__ root, unsigned ph)
{
    __syncthreads();
    if (threadIdx.x == 0) {
        const unsigned gid = blockIdx.x >> 3;
        const unsigned o = __hip_atomic_fetch_add(&c1[gid * 16], 1u,
                              __ATOMIC_ACQ_REL, __HIP_MEMORY_SCOPE_AGENT);
        if (o == 8u * ph - 1u)
            __hip_atomic_fetch_add(root, 1u, __ATOMIC_ACQ_REL,
                                   __HIP_MEMORY_SCOPE_AGENT);
        while (__hip_atomic_load(root, __ATOMIC_ACQUIRE,
                                 __HIP_MEMORY_SCOPE_AGENT) < NGRP * ph)
            __builtin_amdgcn_s_sleep(2);
    }
    __syncthreads();
}

// load a weight slice (rows [n0,n0+rows) of W[*, K]) into LDS, row stride wrs
__device__ __forceinline__ void load_wslice(const ushort_t* __restrict__ W,
                                            int n0, int K, int rows,
                                            ushort_t* dst, int wrs)
{
    const int nch = K >> 3;
    const int total = rows * nch;
    for (int c = threadIdx.x; c < total; c += 256) {
        const int row = c / nch, col = (c - row * nch) * 8;
        *(uint4*)&dst[(size_t)row * wrs + col] =
            *(const uint4*)&W[(size_t)(n0 + row) * K + col];
    }
}

// fragment GEMM: acc[MT][4] over rows mrow0+mt*16, 64 cols (4 ntiles).
// A register-direct (prefetch depth 4), W from LDS slice (local rows).
template <int MT, int NCH1, int NCH2>
__device__ __forceinline__ void frag_gemm(
    const ushort_t* __restrict__ A1, long a1_rs,
    const ushort_t* __restrict__ A2, long a2_rs,
    const ushort_t* w1, const ushort_t* w2, int wrs,
    int mrow0, f32x4 (&acc)[MT][4])
{
    const int lane = threadIdx.x & 63;
    const int lr = lane & 15, lk = (lane >> 4) * 8;
    constexpr int NCH = NCH1 + NCH2;
    constexpr int PF = 4;
    short8 a[PF][MT];

    auto aload = [&](int kc, int slot) {
        const bool p2 = (kc >= NCH1);
        const ushort_t* Ap = p2 ? A2 : A1;
        const long rs = p2 ? a2_rs : a1_rs;
        const int kk = (p2 ? kc - NCH1 : kc) * 32 + lk;
#pragma unroll
        for (int mt = 0; mt < MT; ++mt)
            a[slot][mt] = *(const short8*)(Ap + (size_t)(mrow0 + mt * 16 + lr) * rs + kk);
    };
#pragma unroll
    for (int p = 0; p < PF - 1; ++p) aload(p, p);
#pragma unroll
    for (int kc = 0; kc < NCH; ++kc) {
        if (kc + PF - 1 < NCH) aload(kc + PF - 1, (kc + PF - 1) % PF);
        const bool p2 = (kc >= NCH1);
        const ushort_t* wl = p2 ? w2 : w1;
        const int kk = (p2 ? kc - NCH1 : kc) * 32 + lk;
        short8 wfr[4];
#pragma unroll
        for (int nt = 0; nt < 4; ++nt)
            wfr[nt] = *(const short8*)&wl[(size_t)(nt * 16 + lr) * wrs + kk];
#pragma unroll
        for (int mt = 0; mt < MT; ++mt)
#pragma unroll
            for (int nt = 0; nt < 4; ++nt)
                acc[mt][nt] = __builtin_amdgcn_mfma_f32_16x16x32_bf16(
                    a[kc % PF][mt], wfr[nt], acc[mt][nt], 0, 0, 0);
    }
}

template <int MT>
__device__ __forceinline__ void ep_tanh(f32x4 (&acc)[MT][4], int mrow0, int gc0,
                                        const float* __restrict__ p1,
                                        const float* __restrict__ p2,
                                        ushort_t* __restrict__ obf, long o_rs)
{
    const int lane = threadIdx.x & 63;
    const int lr = lane & 15, rq = (lane >> 4) * 4;
#pragma unroll
    for (int mt = 0; mt < MT; ++mt)
#pragma unroll
        for (int nt = 0; nt < 4; ++nt) {
            const int gcol = gc0 + nt * 16 + lr;
            const float bb = p1[gcol] + p2[gcol];
#pragma unroll
            for (int r = 0; r < 4; ++r) {
                const int grow = mrow0 + mt * 16 + rq + r;
                obf[(size_t)grow * o_rs + gcol] = f2bf(tanhf(acc[mt][nt][r] + bb));
            }
        }
}

template <int MT>
__device__ __forceinline__ void ep_bn(f32x4 (&acc)[MT][4], int mrow0, int gc0,
                                      const float* __restrict__ b,
                                      const float* __restrict__ rm,
                                      const float* __restrict__ rv,
                                      const float* __restrict__ gg,
                                      const float* __restrict__ be,
                                      int Nreal,
                                      ushort_t* __restrict__ obf, long o_rs,
                                      float* __restrict__ of32)
{
    const int lane = threadIdx.x & 63;
    const int lr = lane & 15, rq = (lane >> 4) * 4;
#pragma unroll
    for (int mt = 0; mt < MT; ++mt)
#pragma unroll
        for (int nt = 0; nt < 4; ++nt) {
            const int gcol = gc0 + nt * 16 + lr;
            const bool ok = gcol < Nreal;
            const float s = ok ? gg[gcol] * rsqrtf(rv[gcol] + EPSBN) : 0.f;
            const float c = ok ? (b[gcol] - rm[gcol]) * s + be[gcol] : 0.f;
#pragma unroll
            for (int r = 0; r < 4; ++r) {
                const int grow = mrow0 + mt * 16 + rq + r;
                const float o = ok ? acc[mt][nt][r] * s + c : 0.f;
                obf[(size_t)grow * o_rs + gcol] = f2bf(o);
                if (of32) of32[(size_t)grow * o_rs + gcol] = o;
            }
        }
}

// ---------------------------------------------------------------------------
// Persistent decode: 224 stage-specialized blocks, weights resident in LDS.
// roles: [0,32) cell, [32,96) L1, [96,160) L2, [160,224) L3.
// ---------------------------------------------------------------------------
__global__ __launch_bounds__(256)
void decode_persistent(const ushort_t* __restrict__ seed,
                       const ushort_t* __restrict__ hs,
                       const ushort_t* __restrict__ Wih,
                       const ushort_t* __restrict__ Whh,
                       const ushort_t* __restrict__ W1b,
                       const ushort_t* __restrict__ W2b,
                       const ushort_t* __restrict__ W3b,
                       ushort_t* __restrict__ hdec,
                       ushort_t* __restrict__ zd1, ushort_t* __restrict__ zd2,
                       float* __restrict__ xg, ushort_t* __restrict__ xgb,
                       unsigned* __restrict__ c1, unsigned* __restrict__ root,
                       const float* __restrict__ b_ih, const float* __restrict__ b_hh,
                       const float* __restrict__ b1, const float* __restrict__ rm1,
                       const float* __restrict__ rv1, const float* __restrict__ g1,
                       const float* __restrict__ be1,
                       const float* __restrict__ b2, const float* __restrict__ rm2,
                       const float* __restrict__ rv2, const float* __restrict__ g2,
                       const float* __restrict__ be2,
                       const float* __restrict__ b3, const float* __restrict__ rm3,
                       const float* __restrict__ rv3, const float* __restrict__ g3,
                       const float* __restrict__ be3)
{
    __shared__ ushort_t wlds[66560];   // 133,120 B -> 1 block/CU
    const int id = blockIdx.x;
    const int wave = threadIdx.x >> 6;
    int role, rg, cg;
    if (id < 32)       { role = 0; rg = id >> 3;        cg = id & 7;  }
    else if (id < 96)  { role = 1; rg = (id - 32) >> 3; cg = (id - 32) & 7; }
    else if (id < 160) { role = 2; rg = (id - 96) >> 4; cg = (id - 96) & 15; }
    else               { role = 3; rg = (id - 160) >> 3; cg = (id - 160) & 7; }

    if (role == 0) {
        load_wslice(Wih, cg * 64, FF, 64, wlds, HP);
        load_wslice(Whh, cg * 64, FF, 64, wlds + 64 * HP, HP);
    } else if (role == 1) {
        load_wslice(W1b, cg * 128, FF, 128, wlds, HP);
    } else if (role == 2) {
        load_wslice(W2b, cg * 64, HDP, 64, wlds, 1032);
    } else {
        load_wslice(W3b, cg * 64, HDP, 64, wlds, 1032);
    }
    __syncthreads();

    unsigned ph = 0;
    for (int g = 0; g < 16; ++g) {
        ushort_t* hnew = hdec + (size_t)(g & 1) * BF;
        if (role == 0) {
            const ushort_t* xprev = g ? (xgb + (size_t)(g - 1) * BF) : seed;
            const ushort_t* hprev = g ? (hdec + (size_t)((g - 1) & 1) * BF)
                                      : (hs + (size_t)63 * FF);
            const long h_rs = g ? (long)FF : (long)(TN * FF);
            const int m0 = rg * 128 + wave * 32;
            f32x4 acc[2][4] = {};
            frag_gemm<2, 16, 16>(xprev, FF, hprev, h_rs,
                                 wlds, wlds + 64 * HP, HP, m0, acc);
            ep_tanh<2>(acc, m0, cg * 64, b_ih, b_hh, hnew, FF);
        }
        gbar(c1, root, ++ph);
        if (role == 1) {
            const int m0 = rg * 64 + (wave >> 1) * 32;
            const int gc0 = cg * 128 + (wave & 1) * 64;
            f32x4 acc[2][4] = {};
            frag_gemm<2, 16, 0>(hnew, FF, nullptr, 0,
                                wlds + (wave & 1) * 64 * HP, nullptr, HP, m0, acc);
            ep_bn<2>(acc, m0, gc0, b1, rm1, rv1, g1, be1, HD, zd1, HDP, nullptr);
        }
        gbar(c1, root, ++ph);
        if (role == 2) {
            const int m0 = rg * 128 + wave * 32;
            f32x4 acc[2][4] = {};
            frag_gemm<2, 32, 0>(zd1, HDP, nullptr, 0,
                                wlds, nullptr, 1032, m0, acc);
            ep_bn<2>(acc, m0, cg * 64, b2, rm2, rv2, g2, be2, HD, zd2, HDP, nullptr);
        }
        gbar(c1, root, ++ph);
        if (role == 3) {
            const int m0 = rg * 64 + wave * 16;
            f32x4 acc[1][4] = {};
            frag_gemm<1, 32, 0>(zd2, HDP, nullptr, 0,
                                wlds, nullptr, 1032, m0, acc);
            ep_bn<1>(acc, m0, cg * 64, b3, rm3, rv3, g3, be3, FF,
                     xgb + (size_t)g * BF, FF, xg + (size_t)g * BF);
        }
        gbar(c1, root, ++ph);
    }
}

// ---------------------------------------------------------------------------
__global__ void zero_init(float* __restrict__ sums, unsigned* __restrict__ cnt)
{
    const int i = threadIdx.x + blockIdx.x * blockDim.x;
    if (i < 2) sums[i] = 0.f;
    for (int k = i; k < NGRP * 16 + 1; k += blockDim.x * gridDim.x) cnt[k] = 0u;
}

__global__ void conv_x(const float* __restrict__ x, ushort_t* __restrict__ xb)
{
    const int i = blockIdx.x * blockDim.x + threadIdx.x;
    if (i < MALL * FF / 4) {
        const int e = i * 4;
        const int m = e >> 9;
        const int f = e & (FF - 1);
        const int b = m >> 6, t = m & 63;
        const float4 v = *(const float4*)&x[((size_t)b * TT + t) * FF + f];
        unsigned r0 = (unsigned)f2bf(v.x) | ((unsigned)f2bf(v.y) << 16);
        unsigned r1 = (unsigned)f2bf(v.z) | ((unsigned)f2bf(v.w) << 16);
        *(uint2*)&xb[e] = make_uint2(r0, r1);
    }
}

__global__ void conv_w(const float* __restrict__ src, ushort_t* __restrict__ dst,
                       int Nsrc, int Ksrc, int Npad, int Kpad)
{
    const int i = blockIdx.x * blockDim.x + threadIdx.x;
    if (i < Npad * Kpad) {
        const int n = i / Kpad, k = i - n * Kpad;
        const float v = (n < Nsrc && k < Ksrc) ? src[(size_t)n * Ksrc + k] : 0.f;
        dst[i] = f2bf(v);
    }
}

__global__ void gather_kernel(const float* __restrict__ xgaps,
                              const int* __restrict__ tgap,
                              const float* __restrict__ x,
                              float* __restrict__ out,
                              float* __restrict__ sums)
{
    const int i = blockIdx.x * blockDim.x + threadIdx.x;
    float s = 0.f;
    if (i < BF) {
        const int b = i >> 9, f = i & (FF - 1);
        const int g = tgap[b] - 1;
        const float v = xgaps[((size_t)g * BB + b) * FF + f];
        out[i] = v;
        const float d = v - x[((size_t)b * TT + (TT - 1)) * FF + f];
        s = d * d;
    }
    __shared__ float red[256];
    red[threadIdx.x] = s;
    __syncthreads();
    for (int o = 128; o > 0; o >>= 1) {
        if (threadIdx.x < o) red[threadIdx.x] += red[threadIdx.x + o];
        __syncthreads();
    }
    if (threadIdx.x == 0) atomicAdd(&sums[1], red[0]);
}

__global__ void finalize_kernel(const float* __restrict__ sums,
                                float* __restrict__ out)
{
    if (threadIdx.x == 0 && blockIdx.x == 0) {
        const double n1 = 63.0 * 512.0 * 512.0;
        const double n2 = 512.0 * 512.0;
        out[BF] = (float)((double)sums[0] / (n1 * n1) +
                          (double)sums[1] / (n2 * n2));
    }
}

extern "C" void kernel_launch(void* const* d_in, const int* in_sizes, int n_in,
                              void* d_out, int out_size, void* d_ws, size_t ws_size,
                              hipStream_t stream)
{
    const float* x    = (const float*)d_in[0];
    const int*   tgap = (const int*)d_in[1];
    const float* W_ih = (const float*)d_in[2];
    const float* W_hh = (const float*)d_in[3];
    const float* b_ih = (const float*)d_in[4];
    const float* b_hh = (const float*)d_in[5];
    const float* W1 = (const float*)d_in[6];
    const float* b1 = (const float*)d_in[7];
    const float* g1 = (const float*)d_in[8];
    const float* be1 = (const float*)d_in[9];
    const float* rm1 = (const float*)d_in[10];
    const float* rv1 = (const float*)d_in[11];
    const float* W2 = (const float*)d_in[12];
    const float* b2 = (const float*)d_in[13];
    const float* g2 = (const float*)d_in[14];
    const float* be2 = (const float*)d_in[15];
    const float* rm2 = (const float*)d_in[16];
    const float* rv2 = (const float*)d_in[17];
    const float* W3 = (const float*)d_in[18];
    const float* b3 = (const float*)d_in[19];
    const float* g3 = (const float*)d_in[20];
    const float* be3 = (const float*)d_in[21];
    const float* rm3 = (const float*)d_in[22];
    const float* rv3 = (const float*)d_in[23];
    float* out = (float*)d_out;

    char* p = (char*)d_ws;
    auto take = [&](size_t bytes) -> char* {
        char* r = p; p += (bytes + 63) & ~(size_t)63; return r;
    };
    float*    XWbuf = (float*)take((size_t)MALL * FF * 4);      // 67.1 MB
    ushort_t* hs    = (ushort_t*)take((size_t)MALL * FF * 2);   // 33.5 MB
    ushort_t* xbf   = (ushort_t*)take((size_t)MALL * FF * 2);   // 33.5 MB
    ushort_t* z1    = (ushort_t*)take((size_t)CM * HDP * 2);    // 16.8 MB
    ushort_t* z2    = (ushort_t*)take((size_t)CM * HDP * 2);    // 16.8 MB
    float*    xg    = (float*)take((size_t)16 * BF * 4);        // 16.8 MB
    ushort_t* xgb   = (ushort_t*)take((size_t)16 * BF * 2);     //  8.4 MB
    ushort_t* seed  = (ushort_t*)take((size_t)BF * 2);
    ushort_t* hdec  = (ushort_t*)take((size_t)2 * BF * 2);
    ushort_t* zd1   = (ushort_t*)take((size_t)BB * HDP * 2);
    ushort_t* zd2   = (ushort_t*)take((size_t)BB * HDP * 2);
    ushort_t* Wihb  = (ushort_t*)take((size_t)FF * FF * 2);
    ushort_t* Whhb  = (ushort_t*)take((size_t)FF * FF * 2);
    ushort_t* W1b   = (ushort_t*)take((size_t)HDP * FF * 2);
    ushort_t* W2b   = (ushort_t*)take((size_t)HDP * HDP * 2);
    ushort_t* W3b   = (ushort_t*)take((size_t)FF * HDP * 2);
    float*    sums  = (float*)take(16 * 4);
    unsigned* cnt   = (unsigned*)take((NGRP * 16 + 16) * 4);
    unsigned* root  = cnt + NGRP * 16;

    const dim3 blk(256);

    zero_init<<<dim3(2), blk, 0, stream>>>(sums, cnt);
    conv_x<<<dim3(MALL * FF / 4 / 256), blk, 0, stream>>>(x, xbf);
    conv_w<<<dim3((FF * FF + 255) / 256), blk, 0, stream>>>(W_ih, Wihb, FF, FF, FF, FF);
    conv_w<<<dim3((FF * FF + 255) / 256), blk, 0, stream>>>(W_hh, Whhb, FF, FF, FF, FF);
    conv_w<<<dim3((HDP * FF + 255) / 256), blk, 0, stream>>>(W1, W1b, HD, FF, HDP, FF);
    conv_w<<<dim3((HDP * HDP + 255) / 256), blk, 0, stream>>>(W2, W2b, HD, HD, HDP, HDP);
    conv_w<<<dim3((FF * HDP + 255) / 256), blk, 0, stream>>>(W3, W3b, FF, HD, FF, HDP);

    // 1) XW = x @ W_ih^T + b_ih + b_hh -> fp32
    mfma_gemm<<<dim3(FF / 128, MALL / 128), blk, 0, stream>>>(
        xbf, FF, Wihb, FF, FF, XWbuf, FF, nullptr, 0, 0,
        b_ih, b_hh, nullptr, nullptr, nullptr, nullptr, nullptr, nullptr);

    // 2) recurrence (persistent, batch-split, register W-stream)
    rnn_persistent<<<dim3(BB / 16), blk, 0, stream>>>(Whhb, XWbuf, hs);

    // 3) autoenc over 32768 rows in 4 chunks
    for (int c = 0; c < CH; ++c) {
        const ushort_t* Ac = hs + (size_t)c * CM * FF;
        mfma_gemm<<<dim3(HDP / 128, CM / 128), blk, 0, stream>>>(
            Ac, FF, W1b, FF, HD, z1, HDP, nullptr, 2, 0,
            b1, nullptr, rm1, rv1, g1, be1, nullptr, nullptr);
        mfma_gemm<<<dim3(HDP / 128, CM / 128), blk, 0, stream>>>(
            z1, HDP, W2b, HDP, HD, z2, HDP, nullptr, 2, 0,
            b2, nullptr, rm2, rv2, g2, be2, nullptr, nullptr);
        mfma_gemm<<<dim3(FF / 128, CM / 128), blk, 0, stream>>>(
            z2, HDP, W3b, HDP, FF, nullptr, 0, x, 5, c * CM,
            b3, nullptr, rm3, rv3, g3, be3, seed, sums);
    }

    // 4) decode (persistent, stage-specialized, LDS-resident weights)
    decode_persistent<<<dim3(DNB), blk, 0, stream>>>(
        seed, hs, Wihb, Whhb, W1b, W2b, W3b,
        hdec, zd1, zd2, xg, xgb, cnt, root,
        b_ih, b_hh,
        b1, rm1, rv1, g1, be1,
        b2, rm2, rv2, g2, be2,
        b3, rm3, rv3, g3, be3);

    // 5) gather + finalize
    gather_kernel<<<dim3(BF / 256), blk, 0, stream>>>(xg, tgap, x, out, sums);
    finalize_kernel<<<dim3(1), dim3(64), 0, stream>>>(sums, out);
}

// Round 5
// 2541.180 us; speedup vs baseline: 1.8421x; 1.8421x over previous
//
#include <hip/hip_runtime.h>
#include <math.h>

// forecastRNN on MI355X, round 5.
// Decode fix: the round-4 grid barrier spun on an AGENT-scope ACQUIRE load,
// which invalidates the per-XCD L2 on EVERY spin iteration (gfx950 acquire
// semantics) -> 183 MB HBM refetch/dispatch and ~46 us/step. Replaced with
// per-stage monotonic counters: RELAXED spin (IC-bypass load, no cache ops),
// single ACQUIRE after the condition holds, producer-side single RELEASE
// fetch_add. Roles wait only on their producer stage.

typedef unsigned short ushort_t;
typedef __attribute__((ext_vector_type(8))) short short8;
typedef __attribute__((ext_vector_type(4))) float f32x4;

#define BB 512
#define TT 65
#define TN 64
#define FF 512
#define HD 1000
#define HDP 1024
#define EPSBN 1e-5f
#define BF (BB*FF)          // 262144
#define MALL (BB*TN)        // 32768
#define CH 4
#define CM (MALL/CH)        // 8192
#define HP 520              // LDS h row stride (1040 B)
#define DNB 224
#define NGRP 28

__device__ __forceinline__ ushort_t f2bf(float f) {
    union { float f; unsigned u; } v; v.f = f;
    unsigned r = v.u + 0x7FFFu + ((v.u >> 16) & 1u);
    return (ushort_t)(r >> 16);
}

__device__ __forceinline__ void ld16(const ushort_t* g, ushort_t* l) {
    __builtin_amdgcn_global_load_lds(
        (const __attribute__((address_space(1))) unsigned*)g,
        (__attribute__((address_space(3))) unsigned*)l, 16, 0, 0);
}

// ---------------------------------------------------------------------------
// Large-GEMM kernel (XW precompute + autoenc), 128x128 tile, BK=32.
// ---------------------------------------------------------------------------
__global__ __launch_bounds__(256)
void mfma_gemm(const ushort_t* __restrict__ A, long a_rs,
               const ushort_t* __restrict__ W, int K, int Nreal,
               void* __restrict__ outv, long o_rs,
               const float* __restrict__ aux, int epi, int mbase,
               const float* __restrict__ p1, const float* __restrict__ p2,
               const float* __restrict__ rm, const float* __restrict__ rv,
               const float* __restrict__ gg, const float* __restrict__ be,
               ushort_t* __restrict__ out2, float* __restrict__ sums)
{
    __shared__ ushort_t As[128 * 32];
    __shared__ ushort_t Bs[128 * 32];
    __shared__ float red[256];

    const int tid  = threadIdx.x;
    const int wave = tid >> 6, lane = tid & 63;
    const int wm = wave >> 1, wn = wave & 1;
    const int tileM = blockIdx.y * 128, tileN = blockIdx.x * 128;

    f32x4 acc[4][4] = {};
    const int srow = lane >> 2;
    const int skb  = (lane & 3) * 8;

    for (int kt = 0; kt < K; kt += 32) {
        __syncthreads();
#pragma unroll
        for (int s = 0; s < 2; ++s) {
            const int instr = wave * 2 + s;
            const int row = instr * 16 + srow;
            ld16(A + (size_t)(tileM + row) * a_rs + kt + skb, &As[instr * 512]);
            ld16(W + (size_t)(tileN + row) * (size_t)K + kt + skb, &Bs[instr * 512]);
        }
        __syncthreads();
        const int lr = lane & 15;
        const int lk = (lane >> 4) * 8;
        short8 af[4], bfr[4];
#pragma unroll
        for (int i = 0; i < 4; ++i)
            af[i] = *(const short8*)&As[(wm * 64 + i * 16 + lr) * 32 + lk];
#pragma unroll
        for (int j = 0; j < 4; ++j)
            bfr[j] = *(const short8*)&Bs[(wn * 64 + j * 16 + lr) * 32 + lk];
#pragma unroll
        for (int i = 0; i < 4; ++i)
#pragma unroll
            for (int j = 0; j < 4; ++j)
                acc[i][j] = __builtin_amdgcn_mfma_f32_16x16x32_bf16(
                    af[i], bfr[j], acc[i][j], 0, 0, 0);
    }

    const int lr = lane & 15;
    const int rquad = (lane >> 4) * 4;
    float lsum = 0.f;
#pragma unroll
    for (int i = 0; i < 4; ++i) {
#pragma unroll
        for (int r = 0; r < 4; ++r) {
            const int grow = tileM + wm * 64 + i * 16 + rquad + r;
#pragma unroll
            for (int j = 0; j < 4; ++j) {
                const int gcol = tileN + wn * 64 + j * 16 + lr;
                const float v = acc[i][j][r];
                if (epi == 0) {
                    ((float*)outv)[(size_t)grow * o_rs + gcol] = v + p1[gcol] + p2[gcol];
                } else if (epi == 2) {
                    float o = 0.f;
                    if (gcol < Nreal) {
                        const float s = gg[gcol] * rsqrtf(rv[gcol] + EPSBN);
                        o = (v + p1[gcol] - rm[gcol]) * s + be[gcol];
                    }
                    ((ushort_t*)outv)[(size_t)grow * o_rs + gcol] = f2bf(o);
                } else { // epi 5
                    const float s = gg[gcol] * rsqrtf(rv[gcol] + EPSBN);
                    const float o = (v + p1[gcol] - rm[gcol]) * s + be[gcol];
                    const int gm = mbase + grow;
                    const int b = gm >> 6, tau = gm & 63;
                    if (tau < 63) {
                        const float d = o - aux[((size_t)b * TT + tau + 1) * FF + gcol];
                        lsum += d * d;
                    } else {
                        out2[(size_t)b * FF + gcol] = f2bf(o);
                    }
                }
            }
        }
    }
    if (epi == 5) {
        red[tid] = lsum;
        __syncthreads();
        for (int o = 128; o > 0; o >>= 1) {
            if (tid < o) red[tid] += red[tid + o];
            __syncthreads();
        }
        if (tid == 0) atomicAdd(&sums[0], red[0]);
    }
}

// ---------------------------------------------------------------------------
// Persistent recurrence: 32 blocks x 16 batch rows (unchanged from round 4).
// ---------------------------------------------------------------------------
__global__ __launch_bounds__(256)
void rnn_persistent(const ushort_t* __restrict__ Whh,
                    const float* __restrict__ XW,
                    ushort_t* __restrict__ hs)
{
    __shared__ ushort_t hb[2][16 * HP];
    const int tid = threadIdx.x, wave = tid >> 6, lane = tid & 63;
    const int b0 = blockIdx.x * 16;
    const int lr = lane & 15, lq = lane >> 4;

    for (int it = 0; it < 8; ++it) {
        const int e = (it * 256 + tid) * 4;
        const int row = e >> 9, col = e & 511;
        const size_t gi = ((size_t)(b0 + row) * TN) * FF + col;
        const float4 v = *(const float4*)&XW[gi];
        const ushort_t h0 = f2bf(tanhf(v.x)), h1 = f2bf(tanhf(v.y));
        const ushort_t h2 = f2bf(tanhf(v.z)), h3 = f2bf(tanhf(v.w));
        hb[0][row * HP + col + 0] = h0; hb[0][row * HP + col + 1] = h1;
        hb[0][row * HP + col + 2] = h2; hb[0][row * HP + col + 3] = h3;
        unsigned r0 = (unsigned)h0 | ((unsigned)h1 << 16);
        unsigned r1 = (unsigned)h2 | ((unsigned)h3 << 16);
        *(uint2*)&hs[gi] = make_uint2(r0, r1);
    }
    __syncthreads();

    const int c0 = wave * 128;
    for (int t = 1; t < TN; ++t) {
        const ushort_t* hcur = hb[(t - 1) & 1];
        f32x4 acc[8] = {};
        short8 wf[2][8];
        short8 af[2];
        af[0] = *(const short8*)&hcur[lr * HP + lq * 8];
#pragma unroll
        for (int j = 0; j < 8; ++j)
            wf[0][j] = *(const short8*)(Whh + (size_t)(c0 + j * 16 + lr) * FF + lq * 8);
#pragma unroll
        for (int kc = 0; kc < 16; ++kc) {
            const int b = kc & 1, nb = b ^ 1;
            if (kc < 15) {
                const int kk = (kc + 1) * 32 + lq * 8;
                af[nb] = *(const short8*)&hcur[lr * HP + kk];
#pragma unroll
                for (int j = 0; j < 8; ++j)
                    wf[nb][j] = *(const short8*)(Whh + (size_t)(c0 + j * 16 + lr) * FF + kk);
            }
#pragma unroll
            for (int j = 0; j < 8; ++j)
                acc[j] = __builtin_amdgcn_mfma_f32_16x16x32_bf16(
                    af[b], wf[b][j], acc[j], 0, 0, 0);
        }
        ushort_t* hnxt = hb[t & 1];
#pragma unroll
        for (int j = 0; j < 8; ++j) {
            const int col = c0 + j * 16 + lr;
#pragma unroll
            for (int r = 0; r < 4; ++r) {
                const int row = lq * 4 + r;
                const size_t gi = ((size_t)(b0 + row) * TN + t) * FF + col;
                const ushort_t hv = f2bf(tanhf(acc[j][r] + XW[gi]));
                hnxt[row * HP + col] = hv;
                hs[gi] = hv;
            }
        }
        __syncthreads();
    }
}

// ---------------------------------------------------------------------------
// Producer/consumer handoff: RELAXED spin (no cache ops), single ACQUIRE
// after success; producer: __syncthreads + single RELEASE fetch_add.
// ---------------------------------------------------------------------------
__device__ __forceinline__ void wait_ge(unsigned* __restrict__ c, unsigned tgt)
{
    if (threadIdx.x == 0) {
        while (__hip_atomic_load(c, __ATOMIC_RELAXED,
                                 __HIP_MEMORY_SCOPE_AGENT) < tgt)
            __builtin_amdgcn_s_sleep(1);
        (void)__hip_atomic_load(c, __ATOMIC_ACQUIRE, __HIP_MEMORY_SCOPE_AGENT);
    }
    __syncthreads();
}

__device__ __forceinline__ void arrive(unsigned* __restrict__ c)
{
    __syncthreads();
    if (threadIdx.x == 0)
        __hip_atomic_fetch_add(c, 1u, __ATOMIC_RELEASE,
                               __HIP_MEMORY_SCOPE_AGENT);
}

// load a weight slice (rows [n0,n0+rows) of W[*, K]) into LDS, row stride wrs
__device__ __forceinline__ void load_wslice(const ushort_t* __restrict__ W,
                                            int n0, int K, int rows,
                                            ushort_t* dst, int wrs)
{
    const int nch = K >> 3;
    const int total = rows * nch;
    for (int c = threadIdx.x; c < total; c += 256) {
        const int row = c / nch, col = (c - row * nch) * 8;
        *(uint4*)&dst[(size_t)row * wrs + col] =
            *(const uint4*)&W[(size_t)(n0 + row) * K + col];
    }
}

// fragment GEMM: acc[MT][4] over rows mrow0+mt*16, 64 cols (4 ntiles).
template <int MT, int NCH1, int NCH2>
__device__ __forceinline__ void frag_gemm(
    const ushort_t* __restrict__ A1, long a1_rs,
    const ushort_t* __restrict__ A2, long a2_rs,
    const ushort_t* w1, const ushort_t* w2, int wrs,
    int mrow0, f32x4 (&acc)[MT][4])
{
    const int lane = threadIdx.x & 63;
    const int lr = lane & 15, lk = (lane >> 4) * 8;
    constexpr int NCH = NCH1 + NCH2;
    constexpr int PF = 4;
    short8 a[PF][MT];

    auto aload = [&](int kc, int slot) {
        const bool p2 = (kc >= NCH1);
        const ushort_t* Ap = p2 ? A2 : A1;
        const long rs = p2 ? a2_rs : a1_rs;
        const int kk = (p2 ? kc - NCH1 : kc) * 32 + lk;
#pragma unroll
        for (int mt = 0; mt < MT; ++mt)
            a[slot][mt] = *(const short8*)(Ap + (size_t)(mrow0 + mt * 16 + lr) * rs + kk);
    };
#pragma unroll
    for (int p = 0; p < PF - 1; ++p) aload(p, p);
#pragma unroll
    for (int kc = 0; kc < NCH; ++kc) {
        if (kc + PF - 1 < NCH) aload(kc + PF - 1, (kc + PF - 1) % PF);
        const bool p2 = (kc >= NCH1);
        const ushort_t* wl = p2 ? w2 : w1;
        const int kk = (p2 ? kc - NCH1 : kc) * 32 + lk;
        short8 wfr[4];
#pragma unroll
        for (int nt = 0; nt < 4; ++nt)
            wfr[nt] = *(const short8*)&wl[(size_t)(nt * 16 + lr) * wrs + kk];
#pragma unroll
        for (int mt = 0; mt < MT; ++mt)
#pragma unroll
            for (int nt = 0; nt < 4; ++nt)
                acc[mt][nt] = __builtin_amdgcn_mfma_f32_16x16x32_bf16(
                    a[kc % PF][mt], wfr[nt], acc[mt][nt], 0, 0, 0);
    }
}

template <int MT>
__device__ __forceinline__ void ep_tanh(f32x4 (&acc)[MT][4], int mrow0, int gc0,
                                        const float* __restrict__ p1,
                                        const float* __restrict__ p2,
                                        ushort_t* __restrict__ obf, long o_rs)
{
    const int lane = threadIdx.x & 63;
    const int lr = lane & 15, rq = (lane >> 4) * 4;
#pragma unroll
    for (int mt = 0; mt < MT; ++mt)
#pragma unroll
        for (int nt = 0; nt < 4; ++nt) {
            const int gcol = gc0 + nt * 16 + lr;
            const float bb = p1[gcol] + p2[gcol];
#pragma unroll
            for (int r = 0; r < 4; ++r) {
                const int grow = mrow0 + mt * 16 + rq + r;
                obf[(size_t)grow * o_rs + gcol] = f2bf(tanhf(acc[mt][nt][r] + bb));
            }
        }
}

template <int MT>
__device__ __forceinline__ void ep_bn(f32x4 (&acc)[MT][4], int mrow0, int gc0,
                                      const float* __restrict__ b,
                                      const float* __restrict__ rm,
                                      const float* __restrict__ rv,
                                      const float* __restrict__ gg,
                                      const float* __restrict__ be,
                                      int Nreal,
                                      ushort_t* __restrict__ obf, long o_rs,
                                      float* __restrict__ of32)
{
    const int lane = threadIdx.x & 63;
    const int lr = lane & 15, rq = (lane >> 4) * 4;
#pragma unroll
    for (int mt = 0; mt < MT; ++mt)
#pragma unroll
        for (int nt = 0; nt < 4; ++nt) {
            const int gcol = gc0 + nt * 16 + lr;
            const bool ok = gcol < Nreal;
            const float s = ok ? gg[gcol] * rsqrtf(rv[gcol] + EPSBN) : 0.f;
            const float c = ok ? (b[gcol] - rm[gcol]) * s + be[gcol] : 0.f;
#pragma unroll
            for (int r = 0; r < 4; ++r) {
                const int grow = mrow0 + mt * 16 + rq + r;
                const float o = ok ? acc[mt][nt][r] * s + c : 0.f;
                obf[(size_t)grow * o_rs + gcol] = f2bf(o);
                if (of32) of32[(size_t)grow * o_rs + gcol] = o;
            }
        }
}

// ---------------------------------------------------------------------------
// Persistent decode: 224 stage-specialized blocks, weights resident in LDS.
// roles: [0,32) cell, [32,96) L1, [96,160) L2, [160,224) L3.
// Per-stage monotonic counters; roles wait only on their producer stage.
// ---------------------------------------------------------------------------
__global__ __launch_bounds__(256)
void decode_persistent(const ushort_t* __restrict__ seed,
                       const ushort_t* __restrict__ hs,
                       const ushort_t* __restrict__ Wih,
                       const ushort_t* __restrict__ Whh,
                       const ushort_t* __restrict__ W1b,
                       const ushort_t* __restrict__ W2b,
                       const ushort_t* __restrict__ W3b,
                       ushort_t* __restrict__ hdec,
                       ushort_t* __restrict__ zd1, ushort_t* __restrict__ zd2,
                       float* __restrict__ xg, ushort_t* __restrict__ xgb,
                       unsigned* __restrict__ cnt,
                       const float* __restrict__ b_ih, const float* __restrict__ b_hh,
                       const float* __restrict__ b1, const float* __restrict__ rm1,
                       const float* __restrict__ rv1, const float* __restrict__ g1,
                       const float* __restrict__ be1,
                       const float* __restrict__ b2, const float* __restrict__ rm2,
                       const float* __restrict__ rv2, const float* __restrict__ g2,
                       const float* __restrict__ be2,
                       const float* __restrict__ b3, const float* __restrict__ rm3,
                       const float* __restrict__ rv3, const float* __restrict__ g3,
                       const float* __restrict__ be3)
{
    __shared__ ushort_t wlds[66560];   // 133,120 B -> 1 block/CU
    const int id = blockIdx.x;
    const int wave = threadIdx.x >> 6;
    unsigned* c_cell = cnt + 0;
    unsigned* c_l1   = cnt + 16;
    unsigned* c_l2   = cnt + 32;
    unsigned* c_l3   = cnt + 48;

    if (id < 32) {
        // ---- cell role ----
        const int rg = id >> 3, cg = id & 7;
        load_wslice(Wih, cg * 64, FF, 64, wlds, HP);
        load_wslice(Whh, cg * 64, FF, 64, wlds + 64 * HP, HP);
        __syncthreads();
        for (int g = 0; g < 16; ++g) {
            if (g) wait_ge(c_l3, 64u * g);
            const ushort_t* xprev = g ? (xgb + (size_t)(g - 1) * BF) : seed;
            const ushort_t* hprev = g ? (hdec + (size_t)((g - 1) & 1) * BF)
                                      : (hs + (size_t)63 * FF);
            const long h_rs = g ? (long)FF : (long)(TN * FF);
            ushort_t* hnew = hdec + (size_t)(g & 1) * BF;
            const int m0 = rg * 128 + wave * 32;
            f32x4 acc[2][4] = {};
            frag_gemm<2, 16, 16>(xprev, FF, hprev, h_rs,
                                 wlds, wlds + 64 * HP, HP, m0, acc);
            ep_tanh<2>(acc, m0, cg * 64, b_ih, b_hh, hnew, FF);
            arrive(c_cell);
        }
    } else if (id < 96) {
        // ---- L1 role ----
        const int rg = (id - 32) >> 3, cg = (id - 32) & 7;
        load_wslice(W1b, cg * 128, FF, 128, wlds, HP);
        __syncthreads();
        for (int g = 0; g < 16; ++g) {
            wait_ge(c_cell, 32u * (g + 1));
            const ushort_t* hnew = hdec + (size_t)(g & 1) * BF;
            const int m0 = rg * 64 + (wave >> 1) * 32;
            const int gc0 = cg * 128 + (wave & 1) * 64;
            f32x4 acc[2][4] = {};
            frag_gemm<2, 16, 0>(hnew, FF, nullptr, 0,
                                wlds + (wave & 1) * 64 * HP, nullptr, HP, m0, acc);
            ep_bn<2>(acc, m0, gc0, b1, rm1, rv1, g1, be1, HD, zd1, HDP, nullptr);
            arrive(c_l1);
        }
    } else if (id < 160) {
        // ---- L2 role ----
        const int rg = (id - 96) >> 4, cg = (id - 96) & 15;
        load_wslice(W2b, cg * 64, HDP, 64, wlds, 1032);
        __syncthreads();
        for (int g = 0; g < 16; ++g) {
            wait_ge(c_l1, 64u * (g + 1));
            const int m0 = rg * 128 + wave * 32;
            f32x4 acc[2][4] = {};
            frag_gemm<2, 32, 0>(zd1, HDP, nullptr, 0,
                                wlds, nullptr, 1032, m0, acc);
            ep_bn<2>(acc, m0, cg * 64, b2, rm2, rv2, g2, be2, HD, zd2, HDP, nullptr);
            arrive(c_l2);
        }
    } else {
        // ---- L3 role ----
        const int rg = (id - 160) >> 3, cg = (id - 160) & 7;
        load_wslice(W3b, cg * 64, HDP, 64, wlds, 1032);
        __syncthreads();
        for (int g = 0; g < 16; ++g) {
            wait_ge(c_l2, 64u * (g + 1));
            const int m0 = rg * 64 + wave * 16;
            f32x4 acc[1][4] = {};
            frag_gemm<1, 32, 0>(zd2, HDP, nullptr, 0,
                                wlds, nullptr, 1032, m0, acc);
            ep_bn<1>(acc, m0, cg * 64, b3, rm3, rv3, g3, be3, FF,
                     xgb + (size_t)g * BF, FF, xg + (size_t)g * BF);
            arrive(c_l3);
        }
    }
}

// ---------------------------------------------------------------------------
__global__ void zero_init(float* __restrict__ sums, unsigned* __restrict__ cnt)
{
    const int i = threadIdx.x + blockIdx.x * blockDim.x;
    if (i < 2) sums[i] = 0.f;
    for (int k = i; k < NGRP * 16 + 1; k += blockDim.x * gridDim.x) cnt[k] = 0u;
}

__global__ void conv_x(const float* __restrict__ x, ushort_t* __restrict__ xb)
{
    const int i = blockIdx.x * blockDim.x + threadIdx.x;
    if (i < MALL * FF / 4) {
        const int e = i * 4;
        const int m = e >> 9;
        const int f = e & (FF - 1);
        const int b = m >> 6, t = m & 63;
        const float4 v = *(const float4*)&x[((size_t)b * TT + t) * FF + f];
        unsigned r0 = (unsigned)f2bf(v.x) | ((unsigned)f2bf(v.y) << 16);
        unsigned r1 = (unsigned)f2bf(v.z) | ((unsigned)f2bf(v.w) << 16);
        *(uint2*)&xb[e] = make_uint2(r0, r1);
    }
}

__global__ void conv_w(const float* __restrict__ src, ushort_t* __restrict__ dst,
                       int Nsrc, int Ksrc, int Npad, int Kpad)
{
    const int i = blockIdx.x * blockDim.x + threadIdx.x;
    if (i < Npad * Kpad) {
        const int n = i / Kpad, k = i - n * Kpad;
        const float v = (n < Nsrc && k < Ksrc) ? src[(size_t)n * Ksrc + k] : 0.f;
        dst[i] = f2bf(v);
    }
}

__global__ void gather_kernel(const float* __restrict__ xgaps,
                              const int* __restrict__ tgap,
                              const float* __restrict__ x,
                              float* __restrict__ out,
                              float* __restrict__ sums)
{
    const int i = blockIdx.x * blockDim.x + threadIdx.x;
    float s = 0.f;
    if (i < BF) {
        const int b = i >> 9, f = i & (FF - 1);
        const int g = tgap[b] - 1;
        const float v = xgaps[((size_t)g * BB + b) * FF + f];
        out[i] = v;
        const float d = v - x[((size_t)b * TT + (TT - 1)) * FF + f];
        s = d * d;
    }
    __shared__ float red[256];
    red[threadIdx.x] = s;
    __syncthreads();
    for (int o = 128; o > 0; o >>= 1) {
        if (threadIdx.x < o) red[threadIdx.x] += red[threadIdx.x + o];
        __syncthreads();
    }
    if (threadIdx.x == 0) atomicAdd(&sums[1], red[0]);
}

__global__ void finalize_kernel(const float* __restrict__ sums,
                                float* __restrict__ out)
{
    if (threadIdx.x == 0 && blockIdx.x == 0) {
        const double n1 = 63.0 * 512.0 * 512.0;
        const double n2 = 512.0 * 512.0;
        out[BF] = (float)((double)sums[0] / (n1 * n1) +
                          (double)sums[1] / (n2 * n2));
    }
}

extern "C" void kernel_launch(void* const* d_in, const int* in_sizes, int n_in,
                              void* d_out, int out_size, void* d_ws, size_t ws_size,
                              hipStream_t stream)
{
    const float* x    = (const float*)d_in[0];
    const int*   tgap = (const int*)d_in[1];
    const float* W_ih = (const float*)d_in[2];
    const float* W_hh = (const float*)d_in[3];
    const float* b_ih = (const float*)d_in[4];
    const float* b_hh = (const float*)d_in[5];
    const float* W1 = (const float*)d_in[6];
    const float* b1 = (const float*)d_in[7];
    const float* g1 = (const float*)d_in[8];
    const float* be1 = (const float*)d_in[9];
    const float* rm1 = (const float*)d_in[10];
    const float* rv1 = (const float*)d_in[11];
    const float* W2 = (const float*)d_in[12];
    const float* b2 = (const float*)d_in[13];
    const float* g2 = (const float*)d_in[14];
    const float* be2 = (const float*)d_in[15];
    const float* rm2 = (const float*)d_in[16];
    const float* rv2 = (const float*)d_in[17];
    const float* W3 = (const float*)d_in[18];
    const float* b3 = (const float*)d_in[19];
    const float* g3 = (const float*)d_in[20];
    const float* be3 = (const float*)d_in[21];
    const float* rm3 = (const float*)d_in[22];
    const float* rv3 = (const float*)d_in[23];
    float* out = (float*)d_out;

    char* p = (char*)d_ws;
    auto take = [&](size_t bytes) -> char* {
        char* r = p; p += (bytes + 63) & ~(size_t)63; return r;
    };
    float*    XWbuf = (float*)take((size_t)MALL * FF * 4);      // 67.1 MB
    ushort_t* hs    = (ushort_t*)take((size_t)MALL * FF * 2);   // 33.5 MB
    ushort_t* xbf   = (ushort_t*)take((size_t)MALL * FF * 2);   // 33.5 MB
    ushort_t* z1    = (ushort_t*)take((size_t)CM * HDP * 2);    // 16.8 MB
    ushort_t* z2    = (ushort_t*)take((size_t)CM * HDP * 2);    // 16.8 MB
    float*    xg    = (float*)take((size_t)16 * BF * 4);        // 16.8 MB
    ushort_t* xgb   = (ushort_t*)take((size_t)16 * BF * 2);     //  8.4 MB
    ushort_t* seed  = (ushort_t*)take((size_t)BF * 2);
    ushort_t* hdec  = (ushort_t*)take((size_t)2 * BF * 2);
    ushort_t* zd1   = (ushort_t*)take((size_t)BB * HDP * 2);
    ushort_t* zd2   = (ushort_t*)take((size_t)BB * HDP * 2);
    ushort_t* Wihb  = (ushort_t*)take((size_t)FF * FF * 2);
    ushort_t* Whhb  = (ushort_t*)take((size_t)FF * FF * 2);
    ushort_t* W1b   = (ushort_t*)take((size_t)HDP * FF * 2);
    ushort_t* W2b   = (ushort_t*)take((size_t)HDP * HDP * 2);
    ushort_t* W3b   = (ushort_t*)take((size_t)FF * HDP * 2);
    float*    sums  = (float*)take(16 * 4);
    unsigned* cnt   = (unsigned*)take((NGRP * 16 + 16) * 4);

    const dim3 blk(256);

    zero_init<<<dim3(2), blk, 0, stream>>>(sums, cnt);
    conv_x<<<dim3(MALL * FF / 4 / 256), blk, 0, stream>>>(x, xbf);
    conv_w<<<dim3((FF * FF + 255) / 256), blk, 0, stream>>>(W_ih, Wihb, FF, FF, FF, FF);
    conv_w<<<dim3((FF * FF + 255) / 256), blk, 0, stream>>>(W_hh, Whhb, FF, FF, FF, FF);
    conv_w<<<dim3((HDP * FF + 255) / 256), blk, 0, stream>>>(W1, W1b, HD, FF, HDP, FF);
    conv_w<<<dim3((HDP * HDP + 255) / 256), blk, 0, stream>>>(W2, W2b, HD, HD, HDP, HDP);
    conv_w<<<dim3((FF * HDP + 255) / 256), blk, 0, stream>>>(W3, W3b, FF, HD, FF, HDP);

    // 1) XW = x @ W_ih^T + b_ih + b_hh -> fp32
    mfma_gemm<<<dim3(FF / 128, MALL / 128), blk, 0, stream>>>(
        xbf, FF, Wihb, FF, FF, XWbuf, FF, nullptr, 0, 0,
        b_ih, b_hh, nullptr, nullptr, nullptr, nullptr, nullptr, nullptr);

    // 2) recurrence (persistent, batch-split, register W-stream)
    rnn_persistent<<<dim3(BB / 16), blk, 0, stream>>>(Whhb, XWbuf, hs);

    // 3) autoenc over 32768 rows in 4 chunks
    for (int c = 0; c < CH; ++c) {
        const ushort_t* Ac = hs + (size_t)c * CM * FF;
        mfma_gemm<<<dim3(HDP / 128, CM / 128), blk, 0, stream>>>(
            Ac, FF, W1b, FF, HD, z1, HDP, nullptr, 2, 0,
            b1, nullptr, rm1, rv1, g1, be1, nullptr, nullptr);
        mfma_gemm<<<dim3(HDP / 128, CM / 128), blk, 0, stream>>>(
            z1, HDP, W2b, HDP, HD, z2, HDP, nullptr, 2, 0,
            b2, nullptr, rm2, rv2, g2, be2, nullptr, nullptr);
        mfma_gemm<<<dim3(FF / 128, CM / 128), blk, 0, stream>>>(
            z2, HDP, W3b, HDP, FF, nullptr, 0, x, 5, c * CM,
            b3, nullptr, rm3, rv3, g3, be3, seed, sums);
    }

    // 4) decode (persistent, stage-specialized, per-stage counters)
    decode_persistent<<<dim3(DNB), blk, 0, stream>>>(
        seed, hs, Wihb, Whhb, W1b, W2b, W3b,
        hdec, zd1, zd2, xg, xgb, cnt,
        b_ih, b_hh,
        b1, rm1, rv1, g1, be1,
        b2, rm2, rv2, g2, be2,
        b3, rm3, rv3, g3, be3);

    // 5) gather + finalize
    gather_kernel<<<dim3(BF / 256), blk, 0, stream>>>(xg, tgap, x, out, sums);
    finalize_kernel<<<dim3(1), dim3(64), 0, stream>>>(sums, out);
}

// Round 6
// 2162.207 us; speedup vs baseline: 2.1650x; 1.1753x over previous
//
#include <hip/hip_runtime.h>
#include <math.h>

// forecastRNN on MI355X, round 6.
// - Decode handoff: poll with relaxed agent-scope atomic RMW (fetch_add 0),
//   which executes at the coherence point (a relaxed atomic LOAD can be
//   served stale from the local non-coherent XCD L2 -> ~10us/stage visibility
//   lag seen in round 5). Single ACQUIRE fence after condition holds.
//   Counters spaced 256 B apart.
// - RNN: 3-slot W-prefetch ring (2 chunks ahead), XW register prefetch at
//   step start, fast tanh via __expf.

typedef unsigned short ushort_t;
typedef __attribute__((ext_vector_type(8))) short short8;
typedef __attribute__((ext_vector_type(4))) float f32x4;

#define BB 512
#define TT 65
#define TN 64
#define FF 512
#define HD 1000
#define HDP 1024
#define EPSBN 1e-5f
#define BF (BB*FF)          // 262144
#define MALL (BB*TN)        // 32768
#define CH 4
#define CM (MALL/CH)        // 8192
#define HP 520              // LDS h row stride (1040 B)
#define DNB 224
#define NGRP 28

__device__ __forceinline__ ushort_t f2bf(float f) {
    union { float f; unsigned u; } v; v.f = f;
    unsigned r = v.u + 0x7FFFu + ((v.u >> 16) & 1u);
    return (ushort_t)(r >> 16);
}

__device__ __forceinline__ float ftanh(float x) {
    // 1 - 2/(e^{2x}+1); exact at +-inf saturation, ~1e-7 rel err via v_exp
    const float e = __expf(2.f * x);
    return 1.f - 2.f / (e + 1.f);
}

__device__ __forceinline__ void ld16(const ushort_t* g, ushort_t* l) {
    __builtin_amdgcn_global_load_lds(
        (const __attribute__((address_space(1))) unsigned*)g,
        (__attribute__((address_space(3))) unsigned*)l, 16, 0, 0);
}

// ---------------------------------------------------------------------------
// Large-GEMM kernel (XW precompute + autoenc), 128x128 tile, BK=32.
// ---------------------------------------------------------------------------
__global__ __launch_bounds__(256)
void mfma_gemm(const ushort_t* __restrict__ A, long a_rs,
               const ushort_t* __restrict__ W, int K, int Nreal,
               void* __restrict__ outv, long o_rs,
               const float* __restrict__ aux, int epi, int mbase,
               const float* __restrict__ p1, const float* __restrict__ p2,
               const float* __restrict__ rm, const float* __restrict__ rv,
               const float* __restrict__ gg, const float* __restrict__ be,
               ushort_t* __restrict__ out2, float* __restrict__ sums)
{
    __shared__ ushort_t As[128 * 32];
    __shared__ ushort_t Bs[128 * 32];
    __shared__ float red[256];

    const int tid  = threadIdx.x;
    const int wave = tid >> 6, lane = tid & 63;
    const int wm = wave >> 1, wn = wave & 1;
    const int tileM = blockIdx.y * 128, tileN = blockIdx.x * 128;

    f32x4 acc[4][4] = {};
    const int srow = lane >> 2;
    const int skb  = (lane & 3) * 8;

    for (int kt = 0; kt < K; kt += 32) {
        __syncthreads();
#pragma unroll
        for (int s = 0; s < 2; ++s) {
            const int instr = wave * 2 + s;
            const int row = instr * 16 + srow;
            ld16(A + (size_t)(tileM + row) * a_rs + kt + skb, &As[instr * 512]);
            ld16(W + (size_t)(tileN + row) * (size_t)K + kt + skb, &Bs[instr * 512]);
        }
        __syncthreads();
        const int lr = lane & 15;
        const int lk = (lane >> 4) * 8;
        short8 af[4], bfr[4];
#pragma unroll
        for (int i = 0; i < 4; ++i)
            af[i] = *(const short8*)&As[(wm * 64 + i * 16 + lr) * 32 + lk];
#pragma unroll
        for (int j = 0; j < 4; ++j)
            bfr[j] = *(const short8*)&Bs[(wn * 64 + j * 16 + lr) * 32 + lk];
#pragma unroll
        for (int i = 0; i < 4; ++i)
#pragma unroll
            for (int j = 0; j < 4; ++j)
                acc[i][j] = __builtin_amdgcn_mfma_f32_16x16x32_bf16(
                    af[i], bfr[j], acc[i][j], 0, 0, 0);
    }

    const int lr = lane & 15;
    const int rquad = (lane >> 4) * 4;
    float lsum = 0.f;
#pragma unroll
    for (int i = 0; i < 4; ++i) {
#pragma unroll
        for (int r = 0; r < 4; ++r) {
            const int grow = tileM + wm * 64 + i * 16 + rquad + r;
#pragma unroll
            for (int j = 0; j < 4; ++j) {
                const int gcol = tileN + wn * 64 + j * 16 + lr;
                const float v = acc[i][j][r];
                if (epi == 0) {
                    ((float*)outv)[(size_t)grow * o_rs + gcol] = v + p1[gcol] + p2[gcol];
                } else if (epi == 2) {
                    float o = 0.f;
                    if (gcol < Nreal) {
                        const float s = gg[gcol] * rsqrtf(rv[gcol] + EPSBN);
                        o = (v + p1[gcol] - rm[gcol]) * s + be[gcol];
                    }
                    ((ushort_t*)outv)[(size_t)grow * o_rs + gcol] = f2bf(o);
                } else { // epi 5
                    const float s = gg[gcol] * rsqrtf(rv[gcol] + EPSBN);
                    const float o = (v + p1[gcol] - rm[gcol]) * s + be[gcol];
                    const int gm = mbase + grow;
                    const int b = gm >> 6, tau = gm & 63;
                    if (tau < 63) {
                        const float d = o - aux[((size_t)b * TT + tau + 1) * FF + gcol];
                        lsum += d * d;
                    } else {
                        out2[(size_t)b * FF + gcol] = f2bf(o);
                    }
                }
            }
        }
    }
    if (epi == 5) {
        red[tid] = lsum;
        __syncthreads();
        for (int o = 128; o > 0; o >>= 1) {
            if (tid < o) red[tid] += red[tid + o];
            __syncthreads();
        }
        if (tid == 0) atomicAdd(&sums[0], red[0]);
    }
}

// ---------------------------------------------------------------------------
// Persistent recurrence: 32 blocks x 16 batch rows. 3-slot W prefetch ring
// (2 chunks ahead), XW register prefetch, fast tanh. 1 barrier/step.
// ---------------------------------------------------------------------------
__global__ __launch_bounds__(256)
void rnn_persistent(const ushort_t* __restrict__ Whh,
                    const float* __restrict__ XW,
                    ushort_t* __restrict__ hs)
{
    __shared__ ushort_t hb[2][16 * HP];
    const int tid = threadIdx.x, wave = tid >> 6, lane = tid & 63;
    const int b0 = blockIdx.x * 16;
    const int lr = lane & 15, lq = lane >> 4;
    const int c0 = wave * 128;

    // t = 0: h = tanh(XW_0)
    for (int it = 0; it < 8; ++it) {
        const int e = (it * 256 + tid) * 4;
        const int row = e >> 9, col = e & 511;
        const size_t gi = ((size_t)(b0 + row) * TN) * FF + col;
        const float4 v = *(const float4*)&XW[gi];
        const ushort_t h0 = f2bf(ftanh(v.x)), h1 = f2bf(ftanh(v.y));
        const ushort_t h2 = f2bf(ftanh(v.z)), h3 = f2bf(ftanh(v.w));
        hb[0][row * HP + col + 0] = h0; hb[0][row * HP + col + 1] = h1;
        hb[0][row * HP + col + 2] = h2; hb[0][row * HP + col + 3] = h3;
        unsigned r0 = (unsigned)h0 | ((unsigned)h1 << 16);
        unsigned r1 = (unsigned)h2 | ((unsigned)h3 << 16);
        *(uint2*)&hs[gi] = make_uint2(r0, r1);
    }
    __syncthreads();

    f32x4 acc[8];
    short8 wf[3][8];
    short8 af[3];
    float xw[8][4];

    for (int t = 1; t < TN; ++t) {
        const ushort_t* hcur = hb[(t - 1) & 1];

        // prologue: chunks 0,1 into slots 0,1
#pragma unroll
        for (int s = 0; s < 2; ++s) {
            const int kk = s * 32 + lq * 8;
            af[s] = *(const short8*)&hcur[lr * HP + kk];
#pragma unroll
            for (int j = 0; j < 8; ++j)
                wf[s][j] = *(const short8*)(Whh + (size_t)(c0 + j * 16 + lr) * FF + kk);
        }
        // XW register prefetch for this step (HBM; overlaps the K-loop)
#pragma unroll
        for (int j = 0; j < 8; ++j)
#pragma unroll
            for (int r = 0; r < 4; ++r)
                xw[j][r] = XW[((size_t)(b0 + lq * 4 + r) * TN + t) * FF
                              + c0 + j * 16 + lr];
#pragma unroll
        for (int j = 0; j < 8; ++j) acc[j] = (f32x4){0.f, 0.f, 0.f, 0.f};

#pragma unroll
        for (int kc = 0; kc < 16; ++kc) {
            if (kc + 2 < 16) {
                const int slot = (kc + 2) % 3;
                const int kk = (kc + 2) * 32 + lq * 8;
                af[slot] = *(const short8*)&hcur[lr * HP + kk];
#pragma unroll
                for (int j = 0; j < 8; ++j)
                    wf[slot][j] = *(const short8*)
                        (Whh + (size_t)(c0 + j * 16 + lr) * FF + kk);
            }
            const int b = kc % 3;
#pragma unroll
            for (int j = 0; j < 8; ++j)
                acc[j] = __builtin_amdgcn_mfma_f32_16x16x32_bf16(
                    af[b], wf[b][j], acc[j], 0, 0, 0);
        }

        ushort_t* hnxt = hb[t & 1];
#pragma unroll
        for (int j = 0; j < 8; ++j) {
            const int col = c0 + j * 16 + lr;
#pragma unroll
            for (int r = 0; r < 4; ++r) {
                const int row = lq * 4 + r;
                const size_t gi = ((size_t)(b0 + row) * TN + t) * FF + col;
                const ushort_t hv = f2bf(ftanh(acc[j][r] + xw[j][r]));
                hnxt[row * HP + col] = hv;
                hs[gi] = hv;
            }
        }
        __syncthreads();
    }
}

// ---------------------------------------------------------------------------
// Producer/consumer handoff. Poll with relaxed agent-scope RMW (executes at
// the coherence point -> always fresh, no cache ops); one ACQUIRE fence after.
// ---------------------------------------------------------------------------
__device__ __forceinline__ void wait_ge(unsigned* __restrict__ c, unsigned tgt)
{
    if (threadIdx.x == 0) {
        while (__hip_atomic_fetch_add(c, 0u, __ATOMIC_RELAXED,
                                      __HIP_MEMORY_SCOPE_AGENT) < tgt)
            __builtin_amdgcn_s_sleep(2);
        (void)__hip_atomic_load(c, __ATOMIC_ACQUIRE, __HIP_MEMORY_SCOPE_AGENT);
    }
    __syncthreads();
}

__device__ __forceinline__ void arrive(unsigned* __restrict__ c)
{
    __syncthreads();
    if (threadIdx.x == 0)
        __hip_atomic_fetch_add(c, 1u, __ATOMIC_RELEASE,
                               __HIP_MEMORY_SCOPE_AGENT);
}

// load a weight slice (rows [n0,n0+rows) of W[*, K]) into LDS, row stride wrs
__device__ __forceinline__ void load_wslice(const ushort_t* __restrict__ W,
                                            int n0, int K, int rows,
                                            ushort_t* dst, int wrs)
{
    const int nch = K >> 3;
    const int total = rows * nch;
    for (int c = threadIdx.x; c < total; c += 256) {
        const int row = c / nch, col = (c - row * nch) * 8;
        *(uint4*)&dst[(size_t)row * wrs + col] =
            *(const uint4*)&W[(size_t)(n0 + row) * K + col];
    }
}

// fragment GEMM: acc[MT][4] over rows mrow0+mt*16, 64 cols (4 ntiles).
template <int MT, int NCH1, int NCH2>
__device__ __forceinline__ void frag_gemm(
    const ushort_t* __restrict__ A1, long a1_rs,
    const ushort_t* __restrict__ A2, long a2_rs,
    const ushort_t* w1, const ushort_t* w2, int wrs,
    int mrow0, f32x4 (&acc)[MT][4])
{
    const int lane = threadIdx.x & 63;
    const int lr = lane & 15, lk = (lane >> 4) * 8;
    constexpr int NCH = NCH1 + NCH2;
    constexpr int PF = 4;
    short8 a[PF][MT];

    auto aload = [&](int kc, int slot) {
        const bool p2 = (kc >= NCH1);
        const ushort_t* Ap = p2 ? A2 : A1;
        const long rs = p2 ? a2_rs : a1_rs;
        const int kk = (p2 ? kc - NCH1 : kc) * 32 + lk;
#pragma unroll
        for (int mt = 0; mt < MT; ++mt)
            a[slot][mt] = *(const short8*)(Ap + (size_t)(mrow0 + mt * 16 + lr) * rs + kk);
    };
#pragma unroll
    for (int p = 0; p < PF - 1; ++p) aload(p, p);
#pragma unroll
    for (int kc = 0; kc < NCH; ++kc) {
        if (kc + PF - 1 < NCH) aload(kc + PF - 1, (kc + PF - 1) % PF);
        const bool p2 = (kc >= NCH1);
        const ushort_t* wl = p2 ? w2 : w1;
        const int kk = (p2 ? kc - NCH1 : kc) * 32 + lk;
        short8 wfr[4];
#pragma unroll
        for (int nt = 0; nt < 4; ++nt)
            wfr[nt] = *(const short8*)&wl[(size_t)(nt * 16 + lr) * wrs + kk];
#pragma unroll
        for (int mt = 0; mt < MT; ++mt)
#pragma unroll
            for (int nt = 0; nt < 4; ++nt)
                acc[mt][nt] = __builtin_amdgcn_mfma_f32_16x16x32_bf16(
                    a[kc % PF][mt], wfr[nt], acc[mt][nt], 0, 0, 0);
    }
}

template <int MT>
__device__ __forceinline__ void ep_tanh(f32x4 (&acc)[MT][4], int mrow0, int gc0,
                                        const float* __restrict__ p1,
                                        const float* __restrict__ p2,
                                        ushort_t* __restrict__ obf, long o_rs)
{
    const int lane = threadIdx.x & 63;
    const int lr = lane & 15, rq = (lane >> 4) * 4;
#pragma unroll
    for (int mt = 0; mt < MT; ++mt)
#pragma unroll
        for (int nt = 0; nt < 4; ++nt) {
            const int gcol = gc0 + nt * 16 + lr;
            const float bb = p1[gcol] + p2[gcol];
#pragma unroll
            for (int r = 0; r < 4; ++r) {
                const int grow = mrow0 + mt * 16 + rq + r;
                obf[(size_t)grow * o_rs + gcol] = f2bf(ftanh(acc[mt][nt][r] + bb));
            }
        }
}

template <int MT>
__device__ __forceinline__ void ep_bn(f32x4 (&acc)[MT][4], int mrow0, int gc0,
                                      const float* __restrict__ b,
                                      const float* __restrict__ rm,
                                      const float* __restrict__ rv,
                                      const float* __restrict__ gg,
                                      const float* __restrict__ be,
                                      int Nreal,
                                      ushort_t* __restrict__ obf, long o_rs,
                                      float* __restrict__ of32)
{
    const int lane = threadIdx.x & 63;
    const int lr = lane & 15, rq = (lane >> 4) * 4;
#pragma unroll
    for (int mt = 0; mt < MT; ++mt)
#pragma unroll
        for (int nt = 0; nt < 4; ++nt) {
            const int gcol = gc0 + nt * 16 + lr;
            const bool ok = gcol < Nreal;
            const float s = ok ? gg[gcol] * rsqrtf(rv[gcol] + EPSBN) : 0.f;
            const float c = ok ? (b[gcol] - rm[gcol]) * s + be[gcol] : 0.f;
#pragma unroll
            for (int r = 0; r < 4; ++r) {
                const int grow = mrow0 + mt * 16 + rq + r;
                const float o = ok ? acc[mt][nt][r] * s + c : 0.f;
                obf[(size_t)grow * o_rs + gcol] = f2bf(o);
                if (of32) of32[(size_t)grow * o_rs + gcol] = o;
            }
        }
}

// ---------------------------------------------------------------------------
// Persistent decode: 224 stage-specialized blocks, weights resident in LDS.
// roles: [0,32) cell, [32,96) L1, [96,160) L2, [160,224) L3.
// ---------------------------------------------------------------------------
__global__ __launch_bounds__(256)
void decode_persistent(const ushort_t* __restrict__ seed,
                       const ushort_t* __restrict__ hs,
                       const ushort_t* __restrict__ Wih,
                       const ushort_t* __restrict__ Whh,
                       const ushort_t* __restrict__ W1b,
                       const ushort_t* __restrict__ W2b,
                       const ushort_t* __restrict__ W3b,
                       ushort_t* __restrict__ hdec,
                       ushort_t* __restrict__ zd1, ushort_t* __restrict__ zd2,
                       float* __restrict__ xg, ushort_t* __restrict__ xgb,
                       unsigned* __restrict__ cnt,
                       const float* __restrict__ b_ih, const float* __restrict__ b_hh,
                       const float* __restrict__ b1, const float* __restrict__ rm1,
                       const float* __restrict__ rv1, const float* __restrict__ g1,
                       const float* __restrict__ be1,
                       const float* __restrict__ b2, const float* __restrict__ rm2,
                       const float* __restrict__ rv2, const float* __restrict__ g2,
                       const float* __restrict__ be2,
                       const float* __restrict__ b3, const float* __restrict__ rm3,
                       const float* __restrict__ rv3, const float* __restrict__ g3,
                       const float* __restrict__ be3)
{
    __shared__ ushort_t wlds[66560];   // 133,120 B -> 1 block/CU
    const int id = blockIdx.x;
    const int wave = threadIdx.x >> 6;
    unsigned* c_cell = cnt + 0;        // counters 256 B apart (own lines)
    unsigned* c_l1   = cnt + 64;
    unsigned* c_l2   = cnt + 128;
    unsigned* c_l3   = cnt + 192;

    if (id < 32) {
        // ---- cell role ----
        const int rg = id >> 3, cg = id & 7;
        load_wslice(Wih, cg * 64, FF, 64, wlds, HP);
        load_wslice(Whh, cg * 64, FF, 64, wlds + 64 * HP, HP);
        __syncthreads();
        for (int g = 0; g < 16; ++g) {
            if (g) wait_ge(c_l3, 64u * g);
            const ushort_t* xprev = g ? (xgb + (size_t)(g - 1) * BF) : seed;
            const ushort_t* hprev = g ? (hdec + (size_t)((g - 1) & 1) * BF)
                                      : (hs + (size_t)63 * FF);
            const long h_rs = g ? (long)FF : (long)(TN * FF);
            ushort_t* hnew = hdec + (size_t)(g & 1) * BF;
            const int m0 = rg * 128 + wave * 32;
            f32x4 acc[2][4] = {};
            frag_gemm<2, 16, 16>(xprev, FF, hprev, h_rs,
                                 wlds, wlds + 64 * HP, HP, m0, acc);
            ep_tanh<2>(acc, m0, cg * 64, b_ih, b_hh, hnew, FF);
            arrive(c_cell);
        }
    } else if (id < 96) {
        // ---- L1 role ----
        const int rg = (id - 32) >> 3, cg = (id - 32) & 7;
        load_wslice(W1b, cg * 128, FF, 128, wlds, HP);
        __syncthreads();
        for (int g = 0; g < 16; ++g) {
            wait_ge(c_cell, 32u * (g + 1));
            const ushort_t* hnew = hdec + (size_t)(g & 1) * BF;
            const int m0 = rg * 64 + (wave >> 1) * 32;
            const int gc0 = cg * 128 + (wave & 1) * 64;
            f32x4 acc[2][4] = {};
            frag_gemm<2, 16, 0>(hnew, FF, nullptr, 0,
                                wlds + (wave & 1) * 64 * HP, nullptr, HP, m0, acc);
            ep_bn<2>(acc, m0, gc0, b1, rm1, rv1, g1, be1, HD, zd1, HDP, nullptr);
            arrive(c_l1);
        }
    } else if (id < 160) {
        // ---- L2 role ----
        const int rg = (id - 96) >> 4, cg = (id - 96) & 15;
        load_wslice(W2b, cg * 64, HDP, 64, wlds, 1032);
        __syncthreads();
        for (int g = 0; g < 16; ++g) {
            wait_ge(c_l1, 64u * (g + 1));
            const int m0 = rg * 128 + wave * 32;
            f32x4 acc[2][4] = {};
            frag_gemm<2, 32, 0>(zd1, HDP, nullptr, 0,
                                wlds, nullptr, 1032, m0, acc);
            ep_bn<2>(acc, m0, cg * 64, b2, rm2, rv2, g2, be2, HD, zd2, HDP, nullptr);
            arrive(c_l2);
        }
    } else {
        // ---- L3 role ----
        const int rg = (id - 160) >> 3, cg = (id - 160) & 7;
        load_wslice(W3b, cg * 64, HDP, 64, wlds, 1032);
        __syncthreads();
        for (int g = 0; g < 16; ++g) {
            wait_ge(c_l2, 64u * (g + 1));
            const int m0 = rg * 64 + wave * 16;
            f32x4 acc[1][4] = {};
            frag_gemm<1, 32, 0>(zd2, HDP, nullptr, 0,
                                wlds, nullptr, 1032, m0, acc);
            ep_bn<1>(acc, m0, cg * 64, b3, rm3, rv3, g3, be3, FF,
                     xgb + (size_t)g * BF, FF, xg + (size_t)g * BF);
            arrive(c_l3);
        }
    }
}

// ---------------------------------------------------------------------------
__global__ void zero_init(float* __restrict__ sums, unsigned* __restrict__ cnt)
{
    const int i = threadIdx.x + blockIdx.x * blockDim.x;
    if (i < 2) sums[i] = 0.f;
    for (int k = i; k < NGRP * 16 + 1; k += blockDim.x * gridDim.x) cnt[k] = 0u;
}

__global__ void conv_x(const float* __restrict__ x, ushort_t* __restrict__ xb)
{
    const int i = blockIdx.x * blockDim.x + threadIdx.x;
    if (i < MALL * FF / 4) {
        const int e = i * 4;
        const int m = e >> 9;
        const int f = e & (FF - 1);
        const int b = m >> 6, t = m & 63;
        const float4 v = *(const float4*)&x[((size_t)b * TT + t) * FF + f];
        unsigned r0 = (unsigned)f2bf(v.x) | ((unsigned)f2bf(v.y) << 16);
        unsigned r1 = (unsigned)f2bf(v.z) | ((unsigned)f2bf(v.w) << 16);
        *(uint2*)&xb[e] = make_uint2(r0, r1);
    }
}

__global__ void conv_w(const float* __restrict__ src, ushort_t* __restrict__ dst,
                       int Nsrc, int Ksrc, int Npad, int Kpad)
{
    const int i = blockIdx.x * blockDim.x + threadIdx.x;
    if (i < Npad * Kpad) {
        const int n = i / Kpad, k = i - n * Kpad;
        const float v = (n < Nsrc && k < Ksrc) ? src[(size_t)n * Ksrc + k] : 0.f;
        dst[i] = f2bf(v);
    }
}

__global__ void gather_kernel(const float* __restrict__ xgaps,
                              const int* __restrict__ tgap,
                              const float* __restrict__ x,
                              float* __restrict__ out,
                              float* __restrict__ sums)
{
    const int i = blockIdx.x * blockDim.x + threadIdx.x;
    float s = 0.f;
    if (i < BF) {
        const int b = i >> 9, f = i & (FF - 1);
        const int g = tgap[b] - 1;
        const float v = xgaps[((size_t)g * BB + b) * FF + f];
        out[i] = v;
        const float d = v - x[((size_t)b * TT + (TT - 1)) * FF + f];
        s = d * d;
    }
    __shared__ float red[256];
    red[threadIdx.x] = s;
    __syncthreads();
    for (int o = 128; o > 0; o >>= 1) {
        if (threadIdx.x < o) red[threadIdx.x] += red[threadIdx.x + o];
        __syncthreads();
    }
    if (threadIdx.x == 0) atomicAdd(&sums[1], red[0]);
}

__global__ void finalize_kernel(const float* __restrict__ sums,
                                float* __restrict__ out)
{
    if (threadIdx.x == 0 && blockIdx.x == 0) {
        const double n1 = 63.0 * 512.0 * 512.0;
        const double n2 = 512.0 * 512.0;
        out[BF] = (float)((double)sums[0] / (n1 * n1) +
                          (double)sums[1] / (n2 * n2));
    }
}

extern "C" void kernel_launch(void* const* d_in, const int* in_sizes, int n_in,
                              void* d_out, int out_size, void* d_ws, size_t ws_size,
                              hipStream_t stream)
{
    const float* x    = (const float*)d_in[0];
    const int*   tgap = (const int*)d_in[1];
    const float* W_ih = (const float*)d_in[2];
    const float* W_hh = (const float*)d_in[3];
    const float* b_ih = (const float*)d_in[4];
    const float* b_hh = (const float*)d_in[5];
    const float* W1 = (const float*)d_in[6];
    const float* b1 = (const float*)d_in[7];
    const float* g1 = (const float*)d_in[8];
    const float* be1 = (const float*)d_in[9];
    const float* rm1 = (const float*)d_in[10];
    const float* rv1 = (const float*)d_in[11];
    const float* W2 = (const float*)d_in[12];
    const float* b2 = (const float*)d_in[13];
    const float* g2 = (const float*)d_in[14];
    const float* be2 = (const float*)d_in[15];
    const float* rm2 = (const float*)d_in[16];
    const float* rv2 = (const float*)d_in[17];
    const float* W3 = (const float*)d_in[18];
    const float* b3 = (const float*)d_in[19];
    const float* g3 = (const float*)d_in[20];
    const float* be3 = (const float*)d_in[21];
    const float* rm3 = (const float*)d_in[22];
    const float* rv3 = (const float*)d_in[23];
    float* out = (float*)d_out;

    char* p = (char*)d_ws;
    auto take = [&](size_t bytes) -> char* {
        char* r = p; p += (bytes + 63) & ~(size_t)63; return r;
    };
    float*    XWbuf = (float*)take((size_t)MALL * FF * 4);      // 67.1 MB
    ushort_t* hs    = (ushort_t*)take((size_t)MALL * FF * 2);   // 33.5 MB
    ushort_t* xbf   = (ushort_t*)take((size_t)MALL * FF * 2);   // 33.5 MB
    ushort_t* z1    = (ushort_t*)take((size_t)CM * HDP * 2);    // 16.8 MB
    ushort_t* z2    = (ushort_t*)take((size_t)CM * HDP * 2);    // 16.8 MB
    float*    xg    = (float*)take((size_t)16 * BF * 4);        // 16.8 MB
    ushort_t* xgb   = (ushort_t*)take((size_t)16 * BF * 2);     //  8.4 MB
    ushort_t* seed  = (ushort_t*)take((size_t)BF * 2);
    ushort_t* hdec  = (ushort_t*)take((size_t)2 * BF * 2);
    ushort_t* zd1   = (ushort_t*)take((size_t)BB * HDP * 2);
    ushort_t* zd2   = (ushort_t*)take((size_t)BB * HDP * 2);
    ushort_t* Wihb  = (ushort_t*)take((size_t)FF * FF * 2);
    ushort_t* Whhb  = (ushort_t*)take((size_t)FF * FF * 2);
    ushort_t* W1b   = (ushort_t*)take((size_t)HDP * FF * 2);
    ushort_t* W2b   = (ushort_t*)take((size_t)HDP * HDP * 2);
    ushort_t* W3b   = (ushort_t*)take((size_t)FF * HDP * 2);
    float*    sums  = (float*)take(16 * 4);
    unsigned* cnt   = (unsigned*)take((NGRP * 16 + 16) * 4);

    const dim3 blk(256);

    zero_init<<<dim3(2), blk, 0, stream>>>(sums, cnt);
    conv_x<<<dim3(MALL * FF / 4 / 256), blk, 0, stream>>>(x, xbf);
    conv_w<<<dim3((FF * FF + 255) / 256), blk, 0, stream>>>(W_ih, Wihb, FF, FF, FF, FF);
    conv_w<<<dim3((FF * FF + 255) / 256), blk, 0, stream>>>(W_hh, Whhb, FF, FF, FF, FF);
    conv_w<<<dim3((HDP * FF + 255) / 256), blk, 0, stream>>>(W1, W1b, HD, FF, HDP, FF);
    conv_w<<<dim3((HDP * HDP + 255) / 256), blk, 0, stream>>>(W2, W2b, HD, HD, HDP, HDP);
    conv_w<<<dim3((FF * HDP + 255) / 256), blk, 0, stream>>>(W3, W3b, FF, HD, FF, HDP);

    // 1) XW = x @ W_ih^T + b_ih + b_hh -> fp32
    mfma_gemm<<<dim3(FF / 128, MALL / 128), blk, 0, stream>>>(
        xbf, FF, Wihb, FF, FF, XWbuf, FF, nullptr, 0, 0,
        b_ih, b_hh, nullptr, nullptr, nullptr, nullptr, nullptr, nullptr);

    // 2) recurrence (persistent, batch-split, register W-stream)
    rnn_persistent<<<dim3(BB / 16), blk, 0, stream>>>(Whhb, XWbuf, hs);

    // 3) autoenc over 32768 rows in 4 chunks
    for (int c = 0; c < CH; ++c) {
        const ushort_t* Ac = hs + (size_t)c * CM * FF;
        mfma_gemm<<<dim3(HDP / 128, CM / 128), blk, 0, stream>>>(
            Ac, FF, W1b, FF, HD, z1, HDP, nullptr, 2, 0,
            b1, nullptr, rm1, rv1, g1, be1, nullptr, nullptr);
        mfma_gemm<<<dim3(HDP / 128, CM / 128), blk, 0, stream>>>(
            z1, HDP, W2b, HDP, HD, z2, HDP, nullptr, 2, 0,
            b2, nullptr, rm2, rv2, g2, be2, nullptr, nullptr);
        mfma_gemm<<<dim3(FF / 128, CM / 128), blk, 0, stream>>>(
            z2, HDP, W3b, HDP, FF, nullptr, 0, x, 5, c * CM,
            b3, nullptr, rm3, rv3, g3, be3, seed, sums);
    }

    // 4) decode (persistent, stage-specialized, RMW-poll handoffs)
    decode_persistent<<<dim3(DNB), blk, 0, stream>>>(
        seed, hs, Wihb, Whhb, W1b, W2b, W3b,
        hdec, zd1, zd2, xg, xgb, cnt,
        b_ih, b_hh,
        b1, rm1, rv1, g1, be1,
        b2, rm2, rv2, g2, be2,
        b3, rm3, rv3, g3, be3);

    // 5) gather + finalize
    gather_kernel<<<dim3(BF / 256), blk, 0, stream>>>(xg, tgap, x, out, sums);
    finalize_kernel<<<dim3(1), dim3(64), 0, stream>>>(sums, out);
}